// Round 6
// baseline (159.705 us; speedup 1.0000x reference)
//
#include <hip/hip_runtime.h>

// Self-attention, N=8192, IN_DIM=1024, OUT_DIM(D)=128, fp32 in/out.
// prep (coalesced W^T fp16 transpose, Q scale*log2e folded) ->
// QKV GEMM (128x128 tile, 64x64/wave, XOR-swz LDS) ->
// flash attn (no-max softmax, exp2, R=32 q/wave, XOR-swz LDS, SPLIT=8) -> combine.

#define N_TOK   8192
#define D_IN    1024
#define D_HEAD  128
// 1/sqrt(128) * log2(e): exp(s/sqrt(d)) == exp2(s * QSCALE)
#define QSCALE  (0.08838834764831845f * 1.4426950408889634f)
#define SPLIT   8
#define QB      128
#define KVB     64
#define NIT     ((N_TOK / SPLIT) / KVB)   // 16

typedef _Float16 half8 __attribute__((ext_vector_type(8)));
typedef _Float16 half4 __attribute__((ext_vector_type(4)));
typedef float f32x4 __attribute__((ext_vector_type(4)));

// ---------------- prep: W [1024][128] fp32 -> W^T [3][128][1024] fp16 ----------
// Coalesced: LDS-transpose 32k x 128n tiles. Wq pre-scaled by QSCALE.
__global__ void prep_wt(const float* __restrict__ Wq, const float* __restrict__ Wk,
                        const float* __restrict__ Wv, _Float16* __restrict__ Wt) {
    __shared__ float T[32][129];
    const int mat = blockIdx.y;
    const int k0 = blockIdx.x * 32;
    const int t = threadIdx.x;
    const float* W = (mat == 0) ? Wq : (mat == 1) ? Wk : Wv;

    // load: 32 rows x 128 cols, coalesced (8 threads/row, 16 floats each)
    const int krow = t >> 3, nc0 = (t & 7) * 16;
#pragma unroll
    for (int i = 0; i < 4; i++) {
        float4 f = reinterpret_cast<const float4*>(
            W + (size_t)(k0 + krow) * D_HEAD + nc0)[i];
        T[krow][nc0 + i * 4 + 0] = f.x;
        T[krow][nc0 + i * 4 + 1] = f.y;
        T[krow][nc0 + i * 4 + 2] = f.z;
        T[krow][nc0 + i * 4 + 3] = f.w;
    }
    __syncthreads();

    // store transposed: n = t>>1 (128 rows), 16 k each, contiguous half8 x2
    const int n = t >> 1, kh = (t & 1) * 16;
    half8 h0, h1;
#pragma unroll
    for (int j = 0; j < 8; j++) {
        float v0 = T[kh + j][n];
        float v1 = T[kh + 8 + j][n];
        if (mat == 0) { v0 *= QSCALE; v1 *= QSCALE; }
        h0[j] = (_Float16)v0;
        h1[j] = (_Float16)v1;
    }
    _Float16* dst = Wt + (size_t)mat * 131072 + (size_t)n * D_IN + k0 + kh;
    reinterpret_cast<half8*>(dst)[0] = h0;
    reinterpret_cast<half8*>(dst)[1] = h1;
}

// ---------------- QKV GEMM ----------------
// grid (64, 3): block = 128 z-rows x 128 cols (one mat), 4 waves 2x2, wave 64x64.
// BK=64. LDS: A [128][64] fp16 swz + B [128][64] fp16 swz = 32 KB.
__launch_bounds__(256)
__global__ void qkv_gemm(const float* __restrict__ z, const _Float16* __restrict__ Wt,
                         const float* __restrict__ bq, const float* __restrict__ bk,
                         const float* __restrict__ bv,
                         _Float16* __restrict__ Qs, _Float16* __restrict__ Kh,
                         _Float16* __restrict__ Vt) {
    __shared__ __align__(16) char lds[32768];
    char* Ab = lds;
    char* Bb = lds + 16384;

    const int mat = blockIdx.y;
    const int m0 = blockIdx.x * 128;
    const int t = threadIdx.x;
    const int lane = t & 63, w = t >> 6;
    const int l15 = lane & 15, g = lane >> 4;
    const int wm = w >> 1, wn = w & 1;
    const _Float16* Wm = Wt + (size_t)mat * 131072;

    // staging: row = t>>1, half = t&1 (32-col half of the 64-wide K slice)
    const int srow = t >> 1, sh = t & 1;
    int aw[4], bw[4];
#pragma unroll
    for (int i = 0; i < 4; i++) {
        int u = ((sh * 4 + i) ^ (srow & 7)) << 4;
        aw[i] = srow * 128 + u;
        bw[i] = srow * 128 + u;
    }
    // frag read units (row & 7 == l15 & 7 for both A and B)
    int ru[2];
#pragma unroll
    for (int ct = 0; ct < 2; ct++) ru[ct] = ((ct * 4 + g) ^ (l15 & 7)) << 4;

    f32x4 acc[4][4] = {};

    const float4* zg = reinterpret_cast<const float4*>(
        z + (size_t)(m0 + srow) * D_IN + sh * 32);
    const half8* wg = reinterpret_cast<const half8*>(
        Wm + (size_t)srow * D_IN + sh * 32);

    float4 af[8];
    half8 bf[4];
#pragma unroll
    for (int i = 0; i < 8; i++) af[i] = zg[i];
#pragma unroll
    for (int i = 0; i < 4; i++) bf[i] = wg[i];

    for (int it = 0; it < 16; ++it) {
        __syncthreads();   // previous iteration's frag reads done
#pragma unroll
        for (int j = 0; j < 4; j++) {
            half8 h;
            float4 lo = af[2 * j], hi = af[2 * j + 1];
            h[0]=(_Float16)lo.x; h[1]=(_Float16)lo.y; h[2]=(_Float16)lo.z; h[3]=(_Float16)lo.w;
            h[4]=(_Float16)hi.x; h[5]=(_Float16)hi.y; h[6]=(_Float16)hi.z; h[7]=(_Float16)hi.w;
            *reinterpret_cast<half8*>(Ab + aw[j]) = h;
            *reinterpret_cast<half8*>(Bb + bw[j]) = bf[j];
        }
        __syncthreads();

        if (it < 15) {   // prefetch next K-slice; hides under MFMA below
            zg += 16;
            wg += 8;
#pragma unroll
            for (int i = 0; i < 8; i++) af[i] = zg[i];
#pragma unroll
            for (int i = 0; i < 4; i++) bf[i] = wg[i];
        }

        __builtin_amdgcn_s_setprio(1);
#pragma unroll
        for (int ct = 0; ct < 2; ct++) {
            half8 afr[4], bfr[4];
#pragma unroll
            for (int m16 = 0; m16 < 4; m16++)
                afr[m16] = *reinterpret_cast<half8*>(
                    Ab + (wm * 64 + m16 * 16 + l15) * 128 + ru[ct]);
#pragma unroll
            for (int n16 = 0; n16 < 4; n16++)
                bfr[n16] = *reinterpret_cast<half8*>(
                    Bb + (wn * 64 + n16 * 16 + l15) * 128 + ru[ct]);
#pragma unroll
            for (int m16 = 0; m16 < 4; m16++)
#pragma unroll
                for (int n16 = 0; n16 < 4; n16++)
                    acc[m16][n16] = __builtin_amdgcn_mfma_f32_16x16x32_f16(
                        afr[m16], bfr[n16], acc[m16][n16], 0, 0, 0);
        }
        __builtin_amdgcn_s_setprio(0);
    }

    const float* bias = (mat == 0) ? bq : (mat == 1) ? bk : bv;
    if (mat < 2) {
        _Float16* dst = (mat == 0) ? Qs : Kh;
#pragma unroll
        for (int n16 = 0; n16 < 4; n16++) {
            int n = wn * 64 + n16 * 16 + l15;
            float b = bias[n];
            if (mat == 0) b *= QSCALE;
#pragma unroll
            for (int m16 = 0; m16 < 4; m16++)
#pragma unroll
                for (int r = 0; r < 4; r++) {
                    int m = m0 + wm * 64 + m16 * 16 + g * 4 + r;
                    dst[(size_t)m * D_HEAD + n] = (_Float16)(acc[m16][n16][r] + b);
                }
        }
    } else {
#pragma unroll
        for (int n16 = 0; n16 < 4; n16++) {
            int n = wn * 64 + n16 * 16 + l15;
            float b = bias[n];
#pragma unroll
            for (int m16 = 0; m16 < 4; m16++) {
                half4 pk;
#pragma unroll
                for (int r = 0; r < 4; r++) pk[r] = (_Float16)(acc[m16][n16][r] + b);
                int m = m0 + wm * 64 + m16 * 16 + g * 4;
                *reinterpret_cast<half4*>(&Vt[(size_t)n * N_TOK + m]) = pk;
            }
        }
    }
}

// ---------------- attention (unchanged from round 3) ----------------
// grid (64, SPLIT): 128 q rows per block, 4 waves x 32 q rows each.
// LDS: K [64][128] swz (16KB) | V^T [128][64] swz (16KB) | P 4x[32][64] swz (16KB).
__launch_bounds__(256, 2)
__global__ void attn(const _Float16* __restrict__ Qs, const _Float16* __restrict__ Kh,
                     const _Float16* __restrict__ Vt,
                     _Float16* __restrict__ Opart, float* __restrict__ lpart) {
    __shared__ __align__(16) char lds[49152];
    char* Kb = lds;            // 16384 B
    char* Vb = lds + 16384;    // 16384 B
    char* Pb = lds + 32768;    // 16384 B

    const int t = threadIdx.x;
    const int lane = t & 63, w = t >> 6;
    const int l15 = lane & 15, g = lane >> 4;
    const int q0 = blockIdx.x * QB;
    const int sp = blockIdx.y;
    const int kvA = sp * (N_TOK / SPLIT);

    half8 qa[2][4];
#pragma unroll
    for (int r16 = 0; r16 < 2; r16++)
#pragma unroll
        for (int ct = 0; ct < 4; ct++)
            qa[r16][ct] = *reinterpret_cast<const half8*>(
                Qs + (size_t)(q0 + w * 32 + r16 * 16 + l15) * D_HEAD + ct * 32 + g * 8);

    const int krow = t >> 2, kseg = t & 3;
    const int vd = t >> 1, vh = t & 1;
    int kw[4], vw[4];
#pragma unroll
    for (int i = 0; i < 4; i++) {
        kw[i] = krow * 256 + (((kseg * 4 + i) ^ (krow & 7)) << 4);
        vw[i] = vd * 128 + (((vh * 4 + i) ^ (vd & 7)) << 4);
    }
    int kru[4], vru[2];
#pragma unroll
    for (int ct = 0; ct < 4; ct++) kru[ct] = ((ct * 4 + g) ^ (l15 & 7)) << 4;
#pragma unroll
    for (int s2 = 0; s2 < 2; s2++) vru[s2] = ((s2 * 4 + g) ^ (l15 & 7)) << 4;
    char* Pw = Pb + w * 4096;
    const int phi = l15 >> 3, plo = (l15 & 7) * 2;
    int px[4];
#pragma unroll
    for (int r = 0; r < 4; r++) px[r] = (g * 4 + r) & 7;

    f32x4 o[2][8] = {};
    float lsum[2][4] = {};

    const _Float16* kg = Kh + (size_t)(kvA + krow) * D_HEAD + kseg * 32;
    const _Float16* vg = Vt + (size_t)vd * N_TOK + kvA + vh * 32;
    half8 kr[4], vr[4];
#pragma unroll
    for (int i = 0; i < 4; i++) {
        kr[i] = reinterpret_cast<const half8*>(kg)[i];
        vr[i] = reinterpret_cast<const half8*>(vg)[i];
    }

    for (int it = 0; it < NIT; ++it) {
        __syncthreads();
#pragma unroll
        for (int i = 0; i < 4; i++) {
            *reinterpret_cast<half8*>(Kb + kw[i]) = kr[i];
            *reinterpret_cast<half8*>(Vb + vw[i]) = vr[i];
        }
        __syncthreads();

        if (it + 1 < NIT) {
            kg += (size_t)KVB * D_HEAD;
            vg += KVB;
#pragma unroll
            for (int i = 0; i < 4; i++) {
                kr[i] = reinterpret_cast<const half8*>(kg)[i];
                vr[i] = reinterpret_cast<const half8*>(vg)[i];
            }
        }

        f32x4 sf[2][4] = {};
        __builtin_amdgcn_s_setprio(1);
#pragma unroll
        for (int kt = 0; kt < 4; kt++) {
#pragma unroll
            for (int ct = 0; ct < 4; ct++) {
                half8 kf = *reinterpret_cast<half8*>(Kb + kt * 4096 + l15 * 256 + kru[ct]);
#pragma unroll
                for (int r16 = 0; r16 < 2; r16++)
                    sf[r16][kt] = __builtin_amdgcn_mfma_f32_16x16x32_f16(
                        qa[r16][ct], kf, sf[r16][kt], 0, 0, 0);
            }
        }
        __builtin_amdgcn_s_setprio(0);

#pragma unroll
        for (int r16 = 0; r16 < 2; r16++)
#pragma unroll
            for (int kt = 0; kt < 4; kt++)
#pragma unroll
                for (int r = 0; r < 4; r++) {
                    float p = __builtin_amdgcn_exp2f(sf[r16][kt][r]);
                    lsum[r16][r] += p;
                    *reinterpret_cast<_Float16*>(
                        Pw + r16 * 2048 + (g * 4 + r) * 128 +
                        (((kt * 2 + phi) ^ px[r]) << 4) + plo) = (_Float16)p;
                }

        __builtin_amdgcn_s_setprio(1);
#pragma unroll
        for (int s2 = 0; s2 < 2; s2++) {
            half8 pa[2];
#pragma unroll
            for (int r16 = 0; r16 < 2; r16++)
                pa[r16] = *reinterpret_cast<half8*>(Pw + r16 * 2048 + l15 * 128 + vru[s2]);
#pragma unroll
            for (int dt = 0; dt < 8; dt++) {
                half8 vf = *reinterpret_cast<half8*>(Vb + dt * 2048 + l15 * 128 + vru[s2]);
#pragma unroll
                for (int r16 = 0; r16 < 2; r16++)
                    o[r16][dt] = __builtin_amdgcn_mfma_f32_16x16x32_f16(
                        pa[r16], vf, o[r16][dt], 0, 0, 0);
            }
        }
        __builtin_amdgcn_s_setprio(0);
    }

#pragma unroll
    for (int r16 = 0; r16 < 2; r16++)
#pragma unroll
        for (int r = 0; r < 4; r++) {
            float v = lsum[r16][r];
            v += __shfl_xor(v, 1, 64);
            v += __shfl_xor(v, 2, 64);
            v += __shfl_xor(v, 4, 64);
            v += __shfl_xor(v, 8, 64);
            lsum[r16][r] = v;
        }

    _Float16* Op = Opart + (size_t)sp * N_TOK * D_HEAD;
#pragma unroll
    for (int r16 = 0; r16 < 2; r16++)
#pragma unroll
        for (int dt = 0; dt < 8; dt++)
#pragma unroll
            for (int r = 0; r < 4; r++)
                Op[(size_t)(q0 + w * 32 + r16 * 16 + g * 4 + r) * D_HEAD + dt * 16 + l15] =
                    (_Float16)o[r16][dt][r];
    if (l15 == 0) {
#pragma unroll
        for (int r16 = 0; r16 < 2; r16++)
#pragma unroll
            for (int r = 0; r < 4; r++)
                lpart[sp * N_TOK + q0 + w * 32 + r16 * 16 + g * 4 + r] = lsum[r16][r];
    }
}

// ---------------- combine: out = sum_s O_s / sum_s l_s ----------------
__global__ void combine(const _Float16* __restrict__ Opart, const float* __restrict__ lpart,
                        float* __restrict__ out) {
    int i = blockIdx.x * 256 + threadIdx.x;
    int base = i * 8;
    int m = base >> 7;
    float acc[8] = {};
    float den = 0.f;
#pragma unroll
    for (int s = 0; s < SPLIT; s++) {
        half8 h = *reinterpret_cast<const half8*>(
            Opart + (size_t)s * N_TOK * D_HEAD + base);
#pragma unroll
        for (int j = 0; j < 8; j++) acc[j] += (float)h[j];
        den += lpart[s * N_TOK + m];
    }
    float inv = 1.f / den;
    float4 o0, o1;
    o0.x = acc[0]*inv; o0.y = acc[1]*inv; o0.z = acc[2]*inv; o0.w = acc[3]*inv;
    o1.x = acc[4]*inv; o1.y = acc[5]*inv; o1.z = acc[6]*inv; o1.w = acc[7]*inv;
    reinterpret_cast<float4*>(out + base)[0] = o0;
    reinterpret_cast<float4*>(out + base)[1] = o1;
}

extern "C" void kernel_launch(void* const* d_in, const int* in_sizes, int n_in,
                              void* d_out, int out_size, void* d_ws, size_t ws_size,
                              hipStream_t stream) {
    const float* z  = (const float*)d_in[0];
    const float* Wq = (const float*)d_in[1];
    const float* bq = (const float*)d_in[2];
    const float* Wk = (const float*)d_in[3];
    const float* bk = (const float*)d_in[4];
    const float* Wv = (const float*)d_in[5];
    const float* bv = (const float*)d_in[6];
    float* out = (float*)d_out;

    char* ws = (char*)d_ws;
    _Float16* Wt = (_Float16*)(ws);                                   // 0.75 MB
    _Float16* Qs = (_Float16*)(ws + 786432);                          // 2 MB
    _Float16* Kh = (_Float16*)(ws + 786432 + 2097152);                // 2 MB
    _Float16* Vt = (_Float16*)(ws + 786432 + 2 * 2097152);            // 2 MB (V^T)
    _Float16* Opart = (_Float16*)(ws + 786432 + 3 * 2097152);         // SPLIT*2 MB fp16
    float* lpart = (float*)(ws + 786432 + 3 * 2097152 +
                            (size_t)SPLIT * N_TOK * D_HEAD * 2);      // 0.25 MB

    prep_wt<<<dim3(32, 3), 256, 0, stream>>>(Wq, Wk, Wv, Wt);
    qkv_gemm<<<dim3(64, 3), 256, 0, stream>>>(z, Wt, bq, bk, bv, Qs, Kh, Vt);
    attn<<<dim3(N_TOK / QB, SPLIT), 256, 0, stream>>>(Qs, Kh, Vt, Opart, lpart);
    combine<<<512, 256, 0, stream>>>(Opart, lpart, out);
}